// Round 14
// baseline (117.224 us; speedup 1.0000x reference)
//
#include <hip/hip_runtime.h>
#include <stdint.h>
#include <stddef.h>

// MHA: x[2,2048,1024] -> QKV proj (bf16 MFMA) -> flash attn (H=16, Dh=64) -> out proj.
// R14: R13 + V^T materialized once by a transpose kernel (vt[b][h][d][t], R7-verified
//      layout); attn V staging becomes global_load_lds with pre-swizzled source (same
//      formula as K). stage_v / V reg prefetch / v_perm transpose deleted from the loop.

typedef __attribute__((ext_vector_type(8))) short short8;
typedef __attribute__((ext_vector_type(4))) float f32x4;
typedef __attribute__((ext_vector_type(16))) float f32x16;
typedef __attribute__((ext_vector_type(4))) unsigned short u16x4;

#define MFMA16(a, b, c) __builtin_amdgcn_mfma_f32_16x16x32_bf16((a), (b), (c), 0, 0, 0)
#define MFMA32(a, b, c) __builtin_amdgcn_mfma_f32_32x32x16_bf16((a), (b), (c), 0, 0, 0)
#define AS1 __attribute__((address_space(1)))
#define AS3 __attribute__((address_space(3)))

__device__ __forceinline__ unsigned short f2bf(float f) {
  union { float f; unsigned u; } v; v.f = f;
  unsigned r = v.u + 0x7fffu + ((v.u >> 16) & 1u);   // RNE
  return (unsigned short)(r >> 16);
}

__device__ __forceinline__ float fexp2(float x) {
#if __has_builtin(__builtin_amdgcn_exp2f)
  return __builtin_amdgcn_exp2f(x);     // raw v_exp_f32
#else
  return __builtin_exp2f(x);
#endif
}

__device__ __forceinline__ unsigned cvt_pk_bf16(float lo, float hi) {
  unsigned r;
  asm("v_cvt_pk_bf16_f32 %0, %1, %2" : "=v"(r) : "v"(lo), "v"(hi));
  return r;
}

__device__ __forceinline__ void pl32_swap(unsigned& a, unsigned& b) {
  asm volatile("v_permlane32_swap_b32 %0, %1" : "+v"(a), "+v"(b));
}

__device__ __forceinline__ short8 mk8(unsigned a, unsigned b, unsigned c, unsigned d) {
  union { unsigned u[4]; short8 s; } v;
  v.u[0] = a; v.u[1] = b; v.u[2] = c; v.u[3] = d;
  return v.s;
}

// ---------------- fused prep: [0,4096) prep_w | [4096,8192) cast_x | 8192 pack_bias ----
__global__ __launch_bounds__(256) void prep_all_kernel(const float* __restrict__ x,
                                                       const float* __restrict__ wq,
                                                       const float* __restrict__ wk,
                                                       const float* __restrict__ wv,
                                                       const float* __restrict__ wo,
                                                       const float* __restrict__ bq,
                                                       const float* __restrict__ bk,
                                                       const float* __restrict__ bv,
                                                       unsigned short* __restrict__ xb,
                                                       unsigned short* __restrict__ wt,
                                                       float* __restrict__ bias3) {
  __shared__ unsigned short t_lds[32][33];
  const int bid = blockIdx.x;
  if (bid < 4096) {
    int wsel = bid >> 10;
    int rem = bid & 1023;
    int kb = (rem >> 5) << 5;
    int nb = (rem & 31) << 5;
    const float* W = (wsel == 0) ? wq : (wsel == 1) ? wk : (wsel == 2) ? wv : wo;
    int t = threadIdx.x;
    int r = t >> 3, c = (t & 7) * 4;
    float4 v = *reinterpret_cast<const float4*>(W + (size_t)(kb + r) * 1024 + nb + c);
    t_lds[r][c + 0] = f2bf(v.x);
    t_lds[r][c + 1] = f2bf(v.y);
    t_lds[r][c + 2] = f2bf(v.z);
    t_lds[r][c + 3] = f2bf(v.w);
    __syncthreads();
    u16x4 o;
    o.x = t_lds[c + 0][r]; o.y = t_lds[c + 1][r];
    o.z = t_lds[c + 2][r]; o.w = t_lds[c + 3][r];
    *reinterpret_cast<u16x4*>(wt + (size_t)(wsel * 1024 + nb + r) * 1024 + kb + c) = o;
  } else if (bid < 8192) {
    int i = ((bid - 4096) * 256 + threadIdx.x) * 4;
    float4 v = *reinterpret_cast<const float4*>(x + i);
    u16x4 o;
    o.x = f2bf(v.x); o.y = f2bf(v.y); o.z = f2bf(v.z); o.w = f2bf(v.w);
    *reinterpret_cast<u16x4*>(xb + i) = o;
  } else {
#pragma unroll
    for (int k = 0; k < 12; ++k) {
      int i = k * 256 + threadIdx.x;
      bias3[i] = (i < 1024) ? bq[i] : (i < 2048) ? bk[i - 1024] : bv[i - 2048];
    }
  }
}

// ---------------- V^T transpose: qkvb V-part [4096 tok][1024 d] -> vt[b][h][d][t] ----
__global__ __launch_bounds__(256) void vt_kernel(const unsigned short* __restrict__ qkv,
                                                 unsigned short* __restrict__ vt) {
  __shared__ unsigned short t_lds[32][33];
  const int bid = blockIdx.x;          // 4096 = 128 token-blocks x 32 d-blocks
  const int T0 = (bid >> 5) << 5;
  const int D0 = (bid & 31) << 5;
  const int t = threadIdx.x;
  const int r = t >> 3, c = (t & 7) * 4;
  u16x4 v = *reinterpret_cast<const u16x4*>(qkv + (size_t)(T0 + r) * 3072 + 2048 + D0 + c);
  t_lds[r][c + 0] = v.x;
  t_lds[r][c + 1] = v.y;
  t_lds[r][c + 2] = v.z;
  t_lds[r][c + 3] = v.w;
  __syncthreads();
  u16x4 o;
  o.x = t_lds[c + 0][r]; o.y = t_lds[c + 1][r];
  o.z = t_lds[c + 2][r]; o.w = t_lds[c + 3][r];
  // vt[(b*16+h)][dloc][t]: out[d = D0+r][tok = T0+c..c+3] = in[tok][d]
  const int d = D0 + r;
  const int b = T0 >> 11, h = d >> 6, dloc = d & 63;
  *reinterpret_cast<u16x4*>(vt + (size_t)(b * 16 + h) * 131072 + (size_t)dloc * 2048 +
                            (T0 & 2047) + c) = o;
}

// ---------------- GEMM (R4 config): 2-phase dbuf, single barrier per K-step ----------------
template <typename OutT, bool QS>
__global__ __launch_bounds__(256) void gemm_bt_kernel(const unsigned short* __restrict__ A,
                                                      const unsigned short* __restrict__ Bt,
                                                      const float* __restrict__ bias,
                                                      OutT* __restrict__ C, int N) {
  constexpr int K = 1024;
  __shared__ __align__(16) unsigned short a_lds[2][128 * 32];
  __shared__ __align__(16) unsigned short b_lds[2][128 * 32];
  const int nb = N >> 7;
  const int nwg = nb << 5;
  const int cpx = nwg >> 3;
  const int wg = ((int)blockIdx.x & 7) * cpx + ((int)blockIdx.x >> 3);  // XCD swizzle
  const int bm = wg / nb;
  const int bn = wg % nb;
  const int m0 = bm << 7, n0 = bn << 7;
  const int tid = threadIdx.x;
  const int w = tid >> 6, l = tid & 63;
  const int lr = l & 15, lg = l >> 4;
  const int wm = (w >> 1) << 6, wn = (w & 1) << 6;

  const int q0 = w * 2, q1 = w * 2 + 1;
  const unsigned short* pa0 = A + (size_t)(m0 + q0 * 16 + (l >> 2)) * K + (l & 3) * 8;
  const unsigned short* pa1 = A + (size_t)(m0 + q1 * 16 + (l >> 2)) * K + (l & 3) * 8;
  const unsigned short* pb0 = Bt + (size_t)(n0 + q0 * 16 + (l >> 2)) * K + (l & 3) * 8;
  const unsigned short* pb1 = Bt + (size_t)(n0 + q1 * 16 + (l >> 2)) * K + (l & 3) * 8;

#define GEMM_STAGE(buf, k0)                                                        \
  do {                                                                             \
    __builtin_amdgcn_global_load_lds((const AS1 void*)(pa0 + (k0)),                \
        (AS3 void*)(&a_lds[buf][q0 * 512]), 16, 0, 0);                             \
    __builtin_amdgcn_global_load_lds((const AS1 void*)(pa1 + (k0)),                \
        (AS3 void*)(&a_lds[buf][q1 * 512]), 16, 0, 0);                             \
    __builtin_amdgcn_global_load_lds((const AS1 void*)(pb0 + (k0)),                \
        (AS3 void*)(&b_lds[buf][q0 * 512]), 16, 0, 0);                             \
    __builtin_amdgcn_global_load_lds((const AS1 void*)(pb1 + (k0)),                \
        (AS3 void*)(&b_lds[buf][q1 * 512]), 16, 0, 0);                             \
  } while (0)

  f32x4 acc[4][4] = {};
  GEMM_STAGE(0, 0);
  __syncthreads();

  int cur = 0;
  for (int k0 = 0; k0 < K; k0 += 32) {
    if (k0 + 32 < K) GEMM_STAGE(cur ^ 1, k0 + 32);
    short8 af[4], bfr[4];
#pragma unroll
    for (int i = 0; i < 4; ++i)
      af[i] = *reinterpret_cast<const short8*>(&a_lds[cur][(wm + i * 16 + lr) * 32 + lg * 8]);
#pragma unroll
    for (int i = 0; i < 4; ++i)
      bfr[i] = *reinterpret_cast<const short8*>(&b_lds[cur][(wn + i * 16 + lr) * 32 + lg * 8]);
#pragma unroll
    for (int i = 0; i < 4; ++i)
#pragma unroll
      for (int j = 0; j < 4; ++j)
        acc[i][j] = MFMA16(af[i], bfr[j], acc[i][j]);
    __syncthreads();
    cur ^= 1;
  }
#undef GEMM_STAGE

  const float scale = (QS && n0 < 1024) ? 0.18033688011111f : 1.0f;  // 0.125*log2e
#pragma unroll
  for (int i = 0; i < 4; ++i) {
#pragma unroll
    for (int j = 0; j < 4; ++j) {
#pragma unroll
      for (int r = 0; r < 4; ++r) {
        int m = m0 + wm + i * 16 + lg * 4 + r;
        int n = n0 + wn + j * 16 + lr;
        float val = (acc[i][j][r] + bias[n]) * scale;
        if constexpr (sizeof(OutT) == 2) {
          C[(size_t)m * N + n] = (OutT)f2bf(val);
        } else {
          C[(size_t)m * N + n] = val;
        }
      }
    }
  }
}

// ---------------- flash attention, in-block KV split, all-gll staging ----------------
// grid 512 = (b,h)[32] x qblk[16]; 512 threads = 8 waves; waves 0-3 kv-half 0,
// waves 4-7 kv-half 1. Per-half private 32KB K/V double-buffers; K AND V staged via
// global_load_lds with pre-swizzled sources (V from vt[b][h][d][t]). Fixed-base softmax
// (p=exp2(s)); l via ones-MFMA; halves merged in-LDS.
__global__ __launch_bounds__(512, 4) void attn_kernel(const unsigned short* __restrict__ qkv,
                                                      const unsigned short* __restrict__ vt,
                                                      unsigned short* __restrict__ aout) {
  // layout: half h at h*32768: [K buf0 8K][K buf1 8K][V buf0 8K][V buf1 8K]
  __shared__ __align__(16) char lds[65536];
  const int tid = threadIdx.x;
  const int w = tid >> 6, l = tid & 63;
  const int kv = w >> 2, wsub = w & 3;
  const int lq = l & 31;
  const int hi = l >> 5;
  const int wg = ((int)blockIdx.x & 7) * 64 + ((int)blockIdx.x >> 3);  // XCD swizzle
  const int bh = wg >> 4, qblk = wg & 15;
  const int b = bh >> 4, h = bh & 15;
  const size_t rowbase = (size_t)b * 2048;
  const int q0 = qblk * 128 + wsub * 32;
  const int base = kv << 15;             // per-half LDS region

  // Q fragments (B-operand); Q pre-scaled by 0.125*log2e in GEMM epilogue.
  short8 qf[4];
  {
    const unsigned short* qrow = qkv + (rowbase + q0 + lq) * 3072 + h * 64 + hi * 8;
#pragma unroll
    for (int c = 0; c < 4; ++c)
      qf[c] = *reinterpret_cast<const short8*>(qrow + c * 16);
  }

  // Staging sources (pre-swizzled; gll writes linear). Plane [64 rows][128 B],
  // swizzle (row&7)<<4; wave stages chunks {2wsub,2wsub+1} = rows 16wsub+(l>>3), +8.
  const int colsw = (16 * (l & 7)) ^ ((l >> 3) << 4);
  const char* ksrc = (const char*)(qkv + (rowbase + kv * 1024) * 3072 + 1024 + h * 64) +
                     (size_t)(16 * wsub + (l >> 3)) * 6144 + colsw;
  // V^T rows = d; global row stride 2048 bf16 = 4096 B; t advances within row.
  const char* vsrc = (const char*)vt + (size_t)bh * 262144 +
                     (size_t)(16 * wsub + (l >> 3)) * 4096 + kv * 2048 + colsw;
  const int kdst = wsub * 2048;          // wave-uniform byte offset in the 8 KB plane

  const int swz_lq = (lq & 7) << 4;

  short8 ones;                           // bf16 1.0 x8 (A-operand for l-sum MFMA)
  {
    union { unsigned u[4]; short8 s; } o_;
    o_.u[0] = o_.u[1] = o_.u[2] = o_.u[3] = 0x3F803F80u;
    ones = o_.s;
  }

  f32x16 ot0 = {}, ot1 = {}, lacc = {};

  // prologue: stage K+V tile 0 into buf 0 of own half
  __builtin_amdgcn_global_load_lds((const AS1 void*)ksrc,
                                   (AS3 void*)(lds + base + kdst), 16, 0, 0);
  __builtin_amdgcn_global_load_lds((const AS1 void*)(ksrc + 49152),
                                   (AS3 void*)(lds + base + kdst + 1024), 16, 0, 0);
  __builtin_amdgcn_global_load_lds((const AS1 void*)vsrc,
                                   (AS3 void*)(lds + base + 16384 + kdst), 16, 0, 0);
  __builtin_amdgcn_global_load_lds((const AS1 void*)(vsrc + 32768),
                                   (AS3 void*)(lds + base + 16384 + kdst + 1024), 16, 0, 0);
  ksrc += 393216;                        // 64 K rows ahead
  vsrc += 128;                           // 64 t cols ahead

  int cur = 0;
  for (int t0 = 0; t0 < 1024; t0 += 64) {
    __syncthreads();   // drains all gll into buf[cur]; prev readers done
    const bool more = (t0 + 64) < 1024;
    if (more) {
      char* kd = lds + base + ((cur ^ 1) << 13) + kdst;
      __builtin_amdgcn_global_load_lds((const AS1 void*)ksrc, (AS3 void*)kd, 16, 0, 0);
      __builtin_amdgcn_global_load_lds((const AS1 void*)(ksrc + 49152),
                                       (AS3 void*)(kd + 1024), 16, 0, 0);
      __builtin_amdgcn_global_load_lds((const AS1 void*)vsrc,
                                       (AS3 void*)(kd + 16384), 16, 0, 0);
      __builtin_amdgcn_global_load_lds((const AS1 void*)(vsrc + 32768),
                                       (AS3 void*)(kd + 16384 + 1024), 16, 0, 0);
      ksrc += 393216;
      vsrc += 128;
    }
    const char* kl = lds + base + (cur << 13);
    const char* vl = lds + base + 16384 + (cur << 13);

    // --- QK^T (swapped): lane owns S^T[.][q=lq] ---
    f32x16 s0 = {}, s1 = {};
    __builtin_amdgcn_s_setprio(1);
#pragma unroll
    for (int c = 0; c < 4; ++c) {
      short8 kf0 = *reinterpret_cast<const short8*>(kl + lq * 128 + ((c * 32 + hi * 16) ^ swz_lq));
      short8 kf1 = *reinterpret_cast<const short8*>(kl + (32 + lq) * 128 + ((c * 32 + hi * 16) ^ swz_lq));
      s0 = MFMA32(kf0, qf[c], s0);
      s1 = MFMA32(kf1, qf[c], s1);
    }
    __builtin_amdgcn_s_setprio(0);

    // --- fused per-quadrant: exp2 x8 -> pf -> {PV MFMAs, l-MFMA} ---
#pragma unroll
    for (int c = 0; c < 4; ++c) {
      float t0_, t1_, t2_, t3_, t4_, t5_, t6_, t7_;
      if (c < 2) {
        const int o = c * 8;
        t0_ = fexp2(s0[o + 0]); t1_ = fexp2(s0[o + 1]);
        t2_ = fexp2(s0[o + 2]); t3_ = fexp2(s0[o + 3]);
        t4_ = fexp2(s0[o + 4]); t5_ = fexp2(s0[o + 5]);
        t6_ = fexp2(s0[o + 6]); t7_ = fexp2(s0[o + 7]);
      } else {
        const int o = (c - 2) * 8;
        t0_ = fexp2(s1[o + 0]); t1_ = fexp2(s1[o + 1]);
        t2_ = fexp2(s1[o + 2]); t3_ = fexp2(s1[o + 3]);
        t4_ = fexp2(s1[o + 4]); t5_ = fexp2(s1[o + 5]);
        t6_ = fexp2(s1[o + 6]); t7_ = fexp2(s1[o + 7]);
      }
      unsigned a0 = cvt_pk_bf16(t0_, t1_), a1 = cvt_pk_bf16(t4_, t5_);
      unsigned b0 = cvt_pk_bf16(t2_, t3_), b1 = cvt_pk_bf16(t6_, t7_);
      pl32_swap(a0, a1); pl32_swap(b0, b1);
      short8 pfc = mk8(a0, b0, a1, b1);
      short8 vf0 = *reinterpret_cast<const short8*>(vl + lq * 128 + ((c * 32 + hi * 16) ^ swz_lq));
      short8 vf1 = *reinterpret_cast<const short8*>(vl + (32 + lq) * 128 + ((c * 32 + hi * 16) ^ swz_lq));
      __builtin_amdgcn_s_setprio(1);
      ot0 = MFMA32(vf0, pfc, ot0);
      ot1 = MFMA32(vf1, pfc, ot1);
      lacc = MFMA32(ones, pfc, lacc);
      __builtin_amdgcn_s_setprio(0);
    }
    cur ^= 1;
  }

  // ---- in-block merge: half1 -> LDS (f32 O^T + l), half0 adds+normalizes, all store ----
  __syncthreads();                        // all waves done with K/V planes
  float* lbuf = (float*)lds;              // [128 q] l partials from half 1 (dead K buf0)
  if (kv == 1) {
    float* ob = (float*)(lds + 32768 + wsub * 8192);   // own (dead) region: [64 d][32 q]
#pragma unroll
    for (int r = 0; r < 16; ++r) {
      int d = (r & 3) + 8 * (r >> 2) + 4 * hi;
      ob[d * 32 + lq] = ot0[r];
      ob[(32 + d) * 32 + lq] = ot1[r];
    }
    if (hi == 0) lbuf[wsub * 32 + lq] = lacc[0];
  }
  __syncthreads();
  if (kv == 0) {
    const float* ob = (const float*)(lds + 32768 + wsub * 8192);
    const float inv = 1.0f / (lacc[0] + lbuf[wsub * 32 + lq]);
    char* st = lds + 8192;                // [128 q][64 d] bf16 staging (dead half-0 bufs)
    const int qq = wsub * 32 + lq;
    const int swz = (qq & 7) << 4;
#pragma unroll
    for (int r = 0; r < 16; r += 2) {
      int d = (r & 3) + 8 * (r >> 2) + 4 * hi;
      float a0 = (ot0[r] + ob[d * 32 + lq]) * inv;
      float a1 = (ot0[r + 1] + ob[(d + 1) * 32 + lq]) * inv;
      *(unsigned*)(st + qq * 128 + ((2 * d) ^ swz)) = cvt_pk_bf16(a0, a1);
      float b0_ = (ot1[r] + ob[(32 + d) * 32 + lq]) * inv;
      float b1_ = (ot1[r + 1] + ob[(33 + d) * 32 + lq]) * inv;
      *(unsigned*)(st + qq * 128 + ((2 * (32 + d)) ^ swz)) = cvt_pk_bf16(b0_, b1_);
    }
  }
  __syncthreads();
  {
    int row = tid >> 2;                   // 512 threads -> 128 rows x 32 B
    int c2 = (tid & 3) * 2;
    int swzr = (row & 7) << 4;
    const char* src = lds + 8192 + row * 128;
    short8 v0 = *reinterpret_cast<const short8*>(src + ((c2 * 16) ^ swzr));
    short8 v1 = *reinterpret_cast<const short8*>(src + (((c2 + 1) * 16) ^ swzr));
    unsigned short* orow = aout + (rowbase + qblk * 128 + row) * 1024 + h * 64 + c2 * 8;
    *reinterpret_cast<short8*>(orow) = v0;
    *reinterpret_cast<short8*>(orow + 8) = v1;
  }
}

// ---------------- host ----------------
extern "C" void kernel_launch(void* const* d_in, const int* in_sizes, int n_in,
                              void* d_out, int out_size, void* d_ws, size_t ws_size,
                              hipStream_t stream) {
  const float* x  = (const float*)d_in[0];
  const float* wq = (const float*)d_in[1];
  const float* bq = (const float*)d_in[2];
  const float* wk = (const float*)d_in[3];
  const float* bk = (const float*)d_in[4];
  const float* wv = (const float*)d_in[5];
  const float* bv = (const float*)d_in[6];
  const float* wo = (const float*)d_in[7];
  const float* bo = (const float*)d_in[8];
  float* out = (float*)d_out;

  char* ws = (char*)d_ws;
  // [0,8M): xb during GEMM phase; aob afterwards   [8M,16M): wt
  // [16M,+12K): bias3   [16M+64K,+24M): qkvb   [42.0M,+8M): vt (ws >= 51.5M proven)
  unsigned short* xb    = (unsigned short*)(ws);
  unsigned short* aob   = (unsigned short*)(ws);
  unsigned short* wt    = (unsigned short*)(ws + 8388608);
  float*          bias3 = (float*)(ws + 16777216);
  unsigned short* qkvb  = (unsigned short*)(ws + 16842752);
  unsigned short* vtb   = (unsigned short*)(ws + 42008576);

  // fused prep: wt transpose (4096 blocks) + x cast (4096) + bias pack (1)
  prep_all_kernel<<<8193, 256, 0, stream>>>(x, wq, wk, wv, wo, bq, bk, bv, xb, wt, bias3);

  // fused QKV projection (Q pre-scaled by 0.125*log2e): [4096][3072] bf16
  gemm_bt_kernel<unsigned short, true><<<768, 256, 0, stream>>>(xb, wt, bias3, qkvb, 3072);

  // V^T: qkvb V-part -> vt[b][h][d][t]
  vt_kernel<<<4096, 256, 0, stream>>>(qkvb, vtb);

  // attention (in-block kv split + merge, all-gll staging) -> aob [4096][1024] bf16
  attn_kernel<<<512, 512, 0, stream>>>(qkvb, vtb, aob);

  // output projection -> fp32 d_out [4096][1024]
  gemm_bt_kernel<float, false><<<256, 256, 0, stream>>>(aob, wt + (size_t)3072 * 1024, bo, out, 1024);
}

// Round 15
// 115.881 us; speedup vs baseline: 1.0116x; 1.0116x over previous
//
#include <hip/hip_runtime.h>
#include <stdint.h>
#include <stddef.h>

// MHA: x[2,2048,1024] -> QKV proj (bf16 MFMA) -> flash attn (H=16, Dh=64) -> out proj.
// R15: R14's attn kept (45.5 us, all-gll staging); vt_kernel DELETED — the QKV GEMM's
//      V-part blocks (n0>=2048) transpose their 128x128 tile in (dead) LDS after the
//      K-loop and store straight to vt[b][h][d][t] with coalesced short8 rows.

typedef __attribute__((ext_vector_type(8))) short short8;
typedef __attribute__((ext_vector_type(4))) float f32x4;
typedef __attribute__((ext_vector_type(16))) float f32x16;
typedef __attribute__((ext_vector_type(4))) unsigned short u16x4;

#define MFMA16(a, b, c) __builtin_amdgcn_mfma_f32_16x16x32_bf16((a), (b), (c), 0, 0, 0)
#define MFMA32(a, b, c) __builtin_amdgcn_mfma_f32_32x32x16_bf16((a), (b), (c), 0, 0, 0)
#define AS1 __attribute__((address_space(1)))
#define AS3 __attribute__((address_space(3)))

__device__ __forceinline__ unsigned short f2bf(float f) {
  union { float f; unsigned u; } v; v.f = f;
  unsigned r = v.u + 0x7fffu + ((v.u >> 16) & 1u);   // RNE
  return (unsigned short)(r >> 16);
}

__device__ __forceinline__ float fexp2(float x) {
#if __has_builtin(__builtin_amdgcn_exp2f)
  return __builtin_amdgcn_exp2f(x);     // raw v_exp_f32
#else
  return __builtin_exp2f(x);
#endif
}

__device__ __forceinline__ unsigned cvt_pk_bf16(float lo, float hi) {
  unsigned r;
  asm("v_cvt_pk_bf16_f32 %0, %1, %2" : "=v"(r) : "v"(lo), "v"(hi));
  return r;
}

__device__ __forceinline__ void pl32_swap(unsigned& a, unsigned& b) {
  asm volatile("v_permlane32_swap_b32 %0, %1" : "+v"(a), "+v"(b));
}

__device__ __forceinline__ short8 mk8(unsigned a, unsigned b, unsigned c, unsigned d) {
  union { unsigned u[4]; short8 s; } v;
  v.u[0] = a; v.u[1] = b; v.u[2] = c; v.u[3] = d;
  return v.s;
}

// ---------------- fused prep: [0,4096) prep_w | [4096,8192) cast_x | 8192 pack_bias ----
__global__ __launch_bounds__(256) void prep_all_kernel(const float* __restrict__ x,
                                                       const float* __restrict__ wq,
                                                       const float* __restrict__ wk,
                                                       const float* __restrict__ wv,
                                                       const float* __restrict__ wo,
                                                       const float* __restrict__ bq,
                                                       const float* __restrict__ bk,
                                                       const float* __restrict__ bv,
                                                       unsigned short* __restrict__ xb,
                                                       unsigned short* __restrict__ wt,
                                                       float* __restrict__ bias3) {
  __shared__ unsigned short t_lds[32][33];
  const int bid = blockIdx.x;
  if (bid < 4096) {
    int wsel = bid >> 10;
    int rem = bid & 1023;
    int kb = (rem >> 5) << 5;
    int nb = (rem & 31) << 5;
    const float* W = (wsel == 0) ? wq : (wsel == 1) ? wk : (wsel == 2) ? wv : wo;
    int t = threadIdx.x;
    int r = t >> 3, c = (t & 7) * 4;
    float4 v = *reinterpret_cast<const float4*>(W + (size_t)(kb + r) * 1024 + nb + c);
    t_lds[r][c + 0] = f2bf(v.x);
    t_lds[r][c + 1] = f2bf(v.y);
    t_lds[r][c + 2] = f2bf(v.z);
    t_lds[r][c + 3] = f2bf(v.w);
    __syncthreads();
    u16x4 o;
    o.x = t_lds[c + 0][r]; o.y = t_lds[c + 1][r];
    o.z = t_lds[c + 2][r]; o.w = t_lds[c + 3][r];
    *reinterpret_cast<u16x4*>(wt + (size_t)(wsel * 1024 + nb + r) * 1024 + kb + c) = o;
  } else if (bid < 8192) {
    int i = ((bid - 4096) * 256 + threadIdx.x) * 4;
    float4 v = *reinterpret_cast<const float4*>(x + i);
    u16x4 o;
    o.x = f2bf(v.x); o.y = f2bf(v.y); o.z = f2bf(v.z); o.w = f2bf(v.w);
    *reinterpret_cast<u16x4*>(xb + i) = o;
  } else {
#pragma unroll
    for (int k = 0; k < 12; ++k) {
      int i = k * 256 + threadIdx.x;
      bias3[i] = (i < 1024) ? bq[i] : (i < 2048) ? bk[i - 1024] : bv[i - 2048];
    }
  }
}

// ---------------- GEMM: 2-phase dbuf, single barrier per K-step ----------------
// QS=true (QKV): n0<2048 -> C rows [4096][3072] (Q cols scaled); n0>=2048 -> V tile
// transposed in-LDS and stored to vt[b][h][d][t]. QS=false: plain C = A*Bt^T + bias.
template <typename OutT, bool QS>
__global__ __launch_bounds__(256) void gemm_bt_kernel(const unsigned short* __restrict__ A,
                                                      const unsigned short* __restrict__ Bt,
                                                      const float* __restrict__ bias,
                                                      OutT* __restrict__ C,
                                                      unsigned short* __restrict__ vt,
                                                      int N) {
  constexpr int K = 1024;
  __shared__ __align__(16) char smem[32768];
  unsigned short* a_lds = (unsigned short*)smem;              // [2][4096] elems
  unsigned short* b_lds = (unsigned short*)(smem + 16384);    // [2][4096] elems
  const int nb = N >> 7;
  const int nwg = nb << 5;
  const int cpx = nwg >> 3;
  const int wg = ((int)blockIdx.x & 7) * cpx + ((int)blockIdx.x >> 3);  // XCD swizzle
  const int bm = wg / nb;
  const int bn = wg % nb;
  const int m0 = bm << 7, n0 = bn << 7;
  const int tid = threadIdx.x;
  const int w = tid >> 6, l = tid & 63;
  const int lr = l & 15, lg = l >> 4;
  const int wm = (w >> 1) << 6, wn = (w & 1) << 6;

  const int q0 = w * 2, q1 = w * 2 + 1;
  const unsigned short* pa0 = A + (size_t)(m0 + q0 * 16 + (l >> 2)) * K + (l & 3) * 8;
  const unsigned short* pa1 = A + (size_t)(m0 + q1 * 16 + (l >> 2)) * K + (l & 3) * 8;
  const unsigned short* pb0 = Bt + (size_t)(n0 + q0 * 16 + (l >> 2)) * K + (l & 3) * 8;
  const unsigned short* pb1 = Bt + (size_t)(n0 + q1 * 16 + (l >> 2)) * K + (l & 3) * 8;

#define GEMM_STAGE(buf, k0)                                                        \
  do {                                                                             \
    __builtin_amdgcn_global_load_lds((const AS1 void*)(pa0 + (k0)),                \
        (AS3 void*)(a_lds + (buf) * 4096 + q0 * 512), 16, 0, 0);                   \
    __builtin_amdgcn_global_load_lds((const AS1 void*)(pa1 + (k0)),                \
        (AS3 void*)(a_lds + (buf) * 4096 + q1 * 512), 16, 0, 0);                   \
    __builtin_amdgcn_global_load_lds((const AS1 void*)(pb0 + (k0)),                \
        (AS3 void*)(b_lds + (buf) * 4096 + q0 * 512), 16, 0, 0);                   \
    __builtin_amdgcn_global_load_lds((const AS1 void*)(pb1 + (k0)),                \
        (AS3 void*)(b_lds + (buf) * 4096 + q1 * 512), 16, 0, 0);                   \
  } while (0)

  f32x4 acc[4][4] = {};
  GEMM_STAGE(0, 0);
  __syncthreads();

  int cur = 0;
  for (int k0 = 0; k0 < K; k0 += 32) {
    if (k0 + 32 < K) GEMM_STAGE(cur ^ 1, k0 + 32);
    short8 af[4], bfr[4];
#pragma unroll
    for (int i = 0; i < 4; ++i)
      af[i] = *reinterpret_cast<const short8*>(a_lds + cur * 4096 + (wm + i * 16 + lr) * 32 + lg * 8);
#pragma unroll
    for (int i = 0; i < 4; ++i)
      bfr[i] = *reinterpret_cast<const short8*>(b_lds + cur * 4096 + (wn + i * 16 + lr) * 32 + lg * 8);
#pragma unroll
    for (int i = 0; i < 4; ++i)
#pragma unroll
      for (int j = 0; j < 4; ++j)
        acc[i][j] = MFMA16(af[i], bfr[j], acc[i][j]);
    __syncthreads();   // also separates last frag reads from epilogue LDS reuse
    cur ^= 1;
  }
#undef GEMM_STAGE

  if (QS && n0 >= 2048) {
    // ---- V-part: transpose 128x128 tile in LDS, store to vt[b][h][dloc][t] ----
    // write C^T: tb[n][m] bf16, row 256 B, swizzle byte ^ ((n&7)<<4)
#pragma unroll
    for (int i = 0; i < 4; ++i) {
#pragma unroll
      for (int j = 0; j < 4; ++j) {
        int n_ = wn + j * 16 + lr;          // local d index 0..127
        int m_ = wm + i * 16 + lg * 4;      // local token index, 4 consecutive
        float bv = bias[n0 + n_];
        u16x4 pk;
        pk.x = f2bf(acc[i][j][0] + bv);
        pk.y = f2bf(acc[i][j][1] + bv);
        pk.z = f2bf(acc[i][j][2] + bv);
        pk.w = f2bf(acc[i][j][3] + bv);
        *reinterpret_cast<u16x4*>(smem + n_ * 256 + ((2 * m_) ^ ((n_ & 7) << 4))) = pk;
      }
    }
    __syncthreads();
    // read rows coalesced, store 16B-contiguous: vt[(b*16+h)][d&63][t]
    const int bb = m0 >> 11;
    const int tloc = (m0 & 2047) + (tid & 15) * 8;
#pragma unroll
    for (int p = 0; p < 8; ++p) {
      int n_ = p * 16 + (tid >> 4);
      short8 vrow = *reinterpret_cast<const short8*>(
          smem + n_ * 256 + (((tid & 15) * 16) ^ ((n_ & 7) << 4)));
      int dglob = n0 - 2048 + n_;
      *reinterpret_cast<short8*>(vt + (size_t)(bb * 16 + (dglob >> 6)) * 131072 +
                                 (size_t)(dglob & 63) * 2048 + tloc) = vrow;
    }
  } else {
    const float scale = (QS && n0 < 1024) ? 0.18033688011111f : 1.0f;  // 0.125*log2e
#pragma unroll
    for (int i = 0; i < 4; ++i) {
#pragma unroll
      for (int j = 0; j < 4; ++j) {
#pragma unroll
        for (int r = 0; r < 4; ++r) {
          int m = m0 + wm + i * 16 + lg * 4 + r;
          int n = n0 + wn + j * 16 + lr;
          float val = (acc[i][j][r] + bias[n]) * scale;
          if constexpr (sizeof(OutT) == 2) {
            C[(size_t)m * N + n] = (OutT)f2bf(val);
          } else {
            C[(size_t)m * N + n] = val;
          }
        }
      }
    }
  }
}

// ---------------- flash attention, in-block KV split, all-gll staging (R14) ----------------
__global__ __launch_bounds__(512, 4) void attn_kernel(const unsigned short* __restrict__ qkv,
                                                      const unsigned short* __restrict__ vt,
                                                      unsigned short* __restrict__ aout) {
  // layout: half h at h*32768: [K buf0 8K][K buf1 8K][V buf0 8K][V buf1 8K]
  __shared__ __align__(16) char lds[65536];
  const int tid = threadIdx.x;
  const int w = tid >> 6, l = tid & 63;
  const int kv = w >> 2, wsub = w & 3;
  const int lq = l & 31;
  const int hi = l >> 5;
  const int wg = ((int)blockIdx.x & 7) * 64 + ((int)blockIdx.x >> 3);  // XCD swizzle
  const int bh = wg >> 4, qblk = wg & 15;
  const int b = bh >> 4, h = bh & 15;
  const size_t rowbase = (size_t)b * 2048;
  const int q0 = qblk * 128 + wsub * 32;
  const int base = kv << 15;             // per-half LDS region

  // Q fragments (B-operand); Q pre-scaled by 0.125*log2e in GEMM epilogue.
  short8 qf[4];
  {
    const unsigned short* qrow = qkv + (rowbase + q0 + lq) * 3072 + h * 64 + hi * 8;
#pragma unroll
    for (int c = 0; c < 4; ++c)
      qf[c] = *reinterpret_cast<const short8*>(qrow + c * 16);
  }

  // Staging sources (pre-swizzled; gll writes linear). Plane [64 rows][128 B],
  // swizzle (row&7)<<4; wave stages chunks {2wsub,2wsub+1} = rows 16wsub+(l>>3), +8.
  const int colsw = (16 * (l & 7)) ^ ((l >> 3) << 4);
  const char* ksrc = (const char*)(qkv + (rowbase + kv * 1024) * 3072 + 1024 + h * 64) +
                     (size_t)(16 * wsub + (l >> 3)) * 6144 + colsw;
  // V^T rows = d; global row stride 2048 bf16 = 4096 B; t advances within row.
  const char* vsrc = (const char*)vt + (size_t)bh * 262144 +
                     (size_t)(16 * wsub + (l >> 3)) * 4096 + kv * 2048 + colsw;
  const int kdst = wsub * 2048;          // wave-uniform byte offset in the 8 KB plane

  const int swz_lq = (lq & 7) << 4;

  short8 ones;                           // bf16 1.0 x8 (A-operand for l-sum MFMA)
  {
    union { unsigned u[4]; short8 s; } o_;
    o_.u[0] = o_.u[1] = o_.u[2] = o_.u[3] = 0x3F803F80u;
    ones = o_.s;
  }

  f32x16 ot0 = {}, ot1 = {}, lacc = {};

  // prologue: stage K+V tile 0 into buf 0 of own half
  __builtin_amdgcn_global_load_lds((const AS1 void*)ksrc,
                                   (AS3 void*)(lds + base + kdst), 16, 0, 0);
  __builtin_amdgcn_global_load_lds((const AS1 void*)(ksrc + 49152),
                                   (AS3 void*)(lds + base + kdst + 1024), 16, 0, 0);
  __builtin_amdgcn_global_load_lds((const AS1 void*)vsrc,
                                   (AS3 void*)(lds + base + 16384 + kdst), 16, 0, 0);
  __builtin_amdgcn_global_load_lds((const AS1 void*)(vsrc + 32768),
                                   (AS3 void*)(lds + base + 16384 + kdst + 1024), 16, 0, 0);
  ksrc += 393216;                        // 64 K rows ahead
  vsrc += 128;                           // 64 t cols ahead

  int cur = 0;
  for (int t0 = 0; t0 < 1024; t0 += 64) {
    __syncthreads();   // drains all gll into buf[cur]; prev readers done
    const bool more = (t0 + 64) < 1024;
    if (more) {
      char* kd = lds + base + ((cur ^ 1) << 13) + kdst;
      __builtin_amdgcn_global_load_lds((const AS1 void*)ksrc, (AS3 void*)kd, 16, 0, 0);
      __builtin_amdgcn_global_load_lds((const AS1 void*)(ksrc + 49152),
                                       (AS3 void*)(kd + 1024), 16, 0, 0);
      __builtin_amdgcn_global_load_lds((const AS1 void*)vsrc,
                                       (AS3 void*)(kd + 16384), 16, 0, 0);
      __builtin_amdgcn_global_load_lds((const AS1 void*)(vsrc + 32768),
                                       (AS3 void*)(kd + 16384 + 1024), 16, 0, 0);
      ksrc += 393216;
      vsrc += 128;
    }
    const char* kl = lds + base + (cur << 13);
    const char* vl = lds + base + 16384 + (cur << 13);

    // --- QK^T (swapped): lane owns S^T[.][q=lq] ---
    f32x16 s0 = {}, s1 = {};
    __builtin_amdgcn_s_setprio(1);
#pragma unroll
    for (int c = 0; c < 4; ++c) {
      short8 kf0 = *reinterpret_cast<const short8*>(kl + lq * 128 + ((c * 32 + hi * 16) ^ swz_lq));
      short8 kf1 = *reinterpret_cast<const short8*>(kl + (32 + lq) * 128 + ((c * 32 + hi * 16) ^ swz_lq));
      s0 = MFMA32(kf0, qf[c], s0);
      s1 = MFMA32(kf1, qf[c], s1);
    }
    __builtin_amdgcn_s_setprio(0);

    // --- fused per-quadrant: exp2 x8 -> pf -> {PV MFMAs, l-MFMA} ---
#pragma unroll
    for (int c = 0; c < 4; ++c) {
      float t0_, t1_, t2_, t3_, t4_, t5_, t6_, t7_;
      if (c < 2) {
        const int o = c * 8;
        t0_ = fexp2(s0[o + 0]); t1_ = fexp2(s0[o + 1]);
        t2_ = fexp2(s0[o + 2]); t3_ = fexp2(s0[o + 3]);
        t4_ = fexp2(s0[o + 4]); t5_ = fexp2(s0[o + 5]);
        t6_ = fexp2(s0[o + 6]); t7_ = fexp2(s0[o + 7]);
      } else {
        const int o = (c - 2) * 8;
        t0_ = fexp2(s1[o + 0]); t1_ = fexp2(s1[o + 1]);
        t2_ = fexp2(s1[o + 2]); t3_ = fexp2(s1[o + 3]);
        t4_ = fexp2(s1[o + 4]); t5_ = fexp2(s1[o + 5]);
        t6_ = fexp2(s1[o + 6]); t7_ = fexp2(s1[o + 7]);
      }
      unsigned a0 = cvt_pk_bf16(t0_, t1_), a1 = cvt_pk_bf16(t4_, t5_);
      unsigned b0 = cvt_pk_bf16(t2_, t3_), b1 = cvt_pk_bf16(t6_, t7_);
      pl32_swap(a0, a1); pl32_swap(b0, b1);
      short8 pfc = mk8(a0, b0, a1, b1);
      short8 vf0 = *reinterpret_cast<const short8*>(vl + lq * 128 + ((c * 32 + hi * 16) ^ swz_lq));
      short8 vf1 = *reinterpret_cast<const short8*>(vl + (32 + lq) * 128 + ((c * 32 + hi * 16) ^ swz_lq));
      __builtin_amdgcn_s_setprio(1);
      ot0 = MFMA32(vf0, pfc, ot0);
      ot1 = MFMA32(vf1, pfc, ot1);
      lacc = MFMA32(ones, pfc, lacc);
      __builtin_amdgcn_s_setprio(0);
    }
    cur ^= 1;
  }

  // ---- in-block merge: half1 -> LDS (f32 O^T + l), half0 adds+normalizes, all store ----
  __syncthreads();                        // all waves done with K/V planes
  float* lbuf = (float*)lds;              // [128 q] l partials from half 1 (dead K buf0)
  if (kv == 1) {
    float* ob = (float*)(lds + 32768 + wsub * 8192);   // own (dead) region: [64 d][32 q]
#pragma unroll
    for (int r = 0; r < 16; ++r) {
      int d = (r & 3) + 8 * (r >> 2) + 4 * hi;
      ob[d * 32 + lq] = ot0[r];
      ob[(32 + d) * 32 + lq] = ot1[r];
    }
    if (hi == 0) lbuf[wsub * 32 + lq] = lacc[0];
  }
  __syncthreads();
  if (kv == 0) {
    const float* ob = (const float*)(lds + 32768 + wsub * 8192);
    const float inv = 1.0f / (lacc[0] + lbuf[wsub * 32 + lq]);
    char* st = lds + 8192;                // [128 q][64 d] bf16 staging (dead half-0 bufs)
    const int qq = wsub * 32 + lq;
    const int swz = (qq & 7) << 4;
#pragma unroll
    for (int r = 0; r < 16; r += 2) {
      int d = (r & 3) + 8 * (r >> 2) + 4 * hi;
      float a0 = (ot0[r] + ob[d * 32 + lq]) * inv;
      float a1 = (ot0[r + 1] + ob[(d + 1) * 32 + lq]) * inv;
      *(unsigned*)(st + qq * 128 + ((2 * d) ^ swz)) = cvt_pk_bf16(a0, a1);
      float b0_ = (ot1[r] + ob[(32 + d) * 32 + lq]) * inv;
      float b1_ = (ot1[r + 1] + ob[(33 + d) * 32 + lq]) * inv;
      *(unsigned*)(st + qq * 128 + ((2 * (32 + d)) ^ swz)) = cvt_pk_bf16(b0_, b1_);
    }
  }
  __syncthreads();
  {
    int row = tid >> 2;                   // 512 threads -> 128 rows x 32 B
    int c2 = (tid & 3) * 2;
    int swzr = (row & 7) << 4;
    const char* src = lds + 8192 + row * 128;
    short8 v0 = *reinterpret_cast<const short8*>(src + ((c2 * 16) ^ swzr));
    short8 v1 = *reinterpret_cast<const short8*>(src + (((c2 + 1) * 16) ^ swzr));
    unsigned short* orow = aout + (rowbase + qblk * 128 + row) * 1024 + h * 64 + c2 * 8;
    *reinterpret_cast<short8*>(orow) = v0;
    *reinterpret_cast<short8*>(orow + 8) = v1;
  }
}

// ---------------- host ----------------
extern "C" void kernel_launch(void* const* d_in, const int* in_sizes, int n_in,
                              void* d_out, int out_size, void* d_ws, size_t ws_size,
                              hipStream_t stream) {
  const float* x  = (const float*)d_in[0];
  const float* wq = (const float*)d_in[1];
  const float* bq = (const float*)d_in[2];
  const float* wk = (const float*)d_in[3];
  const float* bk = (const float*)d_in[4];
  const float* wv = (const float*)d_in[5];
  const float* bv = (const float*)d_in[6];
  const float* wo = (const float*)d_in[7];
  const float* bo = (const float*)d_in[8];
  float* out = (float*)d_out;

  char* ws = (char*)d_ws;
  // [0,8M): xb during GEMM phase; aob afterwards   [8M,16M): wt
  // [16M,+12K): bias3   [16M+64K,+24M): qkvb (V third unwritten)   [42.0M,+8M): vt
  unsigned short* xb    = (unsigned short*)(ws);
  unsigned short* aob   = (unsigned short*)(ws);
  unsigned short* wt    = (unsigned short*)(ws + 8388608);
  float*          bias3 = (float*)(ws + 16777216);
  unsigned short* qkvb  = (unsigned short*)(ws + 16842752);
  unsigned short* vtb   = (unsigned short*)(ws + 42008576);

  // fused prep: wt transpose (4096 blocks) + x cast (4096) + bias pack (1)
  prep_all_kernel<<<8193, 256, 0, stream>>>(x, wq, wk, wv, wo, bq, bk, bv, xb, wt, bias3);

  // fused QKV projection: Q|K -> qkvb (Q pre-scaled), V -> vt via in-LDS transpose
  gemm_bt_kernel<unsigned short, true><<<768, 256, 0, stream>>>(xb, wt, bias3, qkvb, vtb, 3072);

  // attention (in-block kv split + merge, all-gll staging) -> aob [4096][1024] bf16
  attn_kernel<<<512, 512, 0, stream>>>(qkvb, vtb, aob);

  // output projection -> fp32 d_out [4096][1024]
  gemm_bt_kernel<float, false><<<256, 256, 0, stream>>>(aob, wt + (size_t)3072 * 1024, bo, out,
                                                        nullptr, 1024);
}